// Round 6
// baseline (5138.076 us; speedup 1.0000x reference)
//
#include <hip/hip_runtime.h>
#include <cstddef>
#include <cstdint>

#define LANG 50257
#define EDIM 512
#define HDIM 1024
#define ADIM 512
#define SLEN 1024
#define NSTEP 25
#define TEMPF 10.0f
#define SOSIDX 1
#define VOFF (NSTEP * LANG)
#define NBLK 256
#define NTHR 1024

// ---- ws byte offsets --------------------------------------------------------
#define OFF_W8     0u           // int8 out_W, permuted rows: 53248*1536
#define OFF_SCL    81788928u    // fp32 per-row scale, 53248
#define OFF_EMBTB  82001920u    // bf16 emb_T 50257*512
#define OFF_P      133465088u   // fp32 P[s][a] 1024*512
#define OFF_EMBT   135562240u   // fp32 embT[a][s] 512*1024
#define OFF_ESC    137659392u   // 1024
#define OFF_H      137663488u   // 2*1024
#define OFF_HPROJ8 137671680u   // 8*512
#define OFF_EANX8  137688064u   // 8*512
#define OFF_DENWP  137704448u   // 256
#define OFF_SDENP  137705472u   // 256
#define OFF_ATTN   137706496u   // 512
#define OFF_BAR    137708544u   // flags[256] + gfl[16] + go (memset per launch)

__device__ __forceinline__ float wred(float x) {
#pragma unroll
  for (int off = 32; off; off >>= 1) x += __shfl_down(x, off);
  return x;
}

__device__ __forceinline__ unsigned short f2bf(float x) {
  unsigned u = __float_as_uint(x);
  u = u + 0x7FFFu + ((u >> 16) & 1u);   // RNE
  return (unsigned short)(u >> 16);
}

// flag-broadcast barrier: no serialized RMWs. Monotonic rounds; memset once.
__device__ __forceinline__ void gridbar(unsigned* bar, int bid, unsigned round) {
  __syncthreads();
  const int tid = threadIdx.x;
  if (tid == 0) {
    __threadfence();
    __hip_atomic_store(&bar[bid], round, __ATOMIC_RELEASE, __HIP_MEMORY_SCOPE_AGENT);
  }
  if ((bid & 15) == 0 && tid < 64) {           // group leader, wave 0
    unsigned v;
    do {
      v = (tid < 16) ? __hip_atomic_load(&bar[bid + tid], __ATOMIC_ACQUIRE, __HIP_MEMORY_SCOPE_AGENT) : round;
    } while (__any(v < round));
    if (tid == 0)
      __hip_atomic_store(&bar[256 + (bid >> 4)], round, __ATOMIC_RELEASE, __HIP_MEMORY_SCOPE_AGENT);
  }
  if (bid == 0 && tid < 64) {                  // root
    unsigned v;
    do {
      v = (tid < 16) ? __hip_atomic_load(&bar[256 + tid], __ATOMIC_ACQUIRE, __HIP_MEMORY_SCOPE_AGENT) : round;
    } while (__any(v < round));
    if (tid == 0)
      __hip_atomic_store(&bar[272], round, __ATOMIC_RELEASE, __HIP_MEMORY_SCOPE_AGENT);
  }
  if (tid == 0) {
    while (__hip_atomic_load(&bar[272], __ATOMIC_ACQUIRE, __HIP_MEMORY_SCOPE_AGENT) < round)
      __builtin_amdgcn_s_sleep(1);
  }
  __syncthreads();
}

#define DOT8(u, kk)                                                      \
  {                                                                      \
    acc += (float)((int)((u).x << 24) >> 24) * xr[(kk) * 8 + 0];         \
    acc += (float)((int)((u).x << 16) >> 24) * xr[(kk) * 8 + 1];         \
    acc += (float)((int)((u).x << 8)  >> 24) * xr[(kk) * 8 + 2];         \
    acc += (float)((int)(u).x >> 24)          * xr[(kk) * 8 + 3];        \
    acc += (float)((int)((u).y << 24) >> 24) * xr[(kk) * 8 + 4];         \
    acc += (float)((int)((u).y << 16) >> 24) * xr[(kk) * 8 + 5];         \
    acc += (float)((int)((u).y << 8)  >> 24) * xr[(kk) * 8 + 6];         \
    acc += (float)((int)(u).y >> 24)          * xr[(kk) * 8 + 7];        \
  }

__global__ __launch_bounds__(NTHR, 4) void k_decoder(
    const float* __restrict__ hidden, const float* __restrict__ emb_src,
    const float* __restrict__ emb_T,  const float* __restrict__ W_ih,
    const float* __restrict__ W_hh,   const float* __restrict__ b_ih,
    const float* __restrict__ b_hh,   const float* __restrict__ W1,
    const float* __restrict__ b1,     const float* __restrict__ vvec,
    const float* __restrict__ out_W,  const float* __restrict__ out_b,
    float* __restrict__ out, char* __restrict__ wsb) {
  __shared__ __align__(16) float smem[9776];
  const int tid = threadIdx.x, bid = blockIdx.x;
  const int wid = tid >> 6, lane = tid & 63;

  float* P      = (float*)(wsb + OFF_P);
  float* embT   = (float*)(wsb + OFF_EMBT);
  float* esc    = (float*)(wsb + OFF_ESC);
  float* hws    = (float*)(wsb + OFF_H);
  float* hproj8 = (float*)(wsb + OFF_HPROJ8);
  float* eanx8  = (float*)(wsb + OFF_EANX8);
  float* denwp  = (float*)(wsb + OFF_DENWP);
  float* sdenp  = (float*)(wsb + OFF_SDENP);
  float* attn   = (float*)(wsb + OFF_ATTN);
  float* scl    = (float*)(wsb + OFF_SCL);
  unsigned* bar = (unsigned*)(wsb + OFF_BAR);
  const uint2* W8r = (const uint2*)(wsb + OFF_W8);
  const uint4* eT4 = (const uint4*)(wsb + OFF_EMBTB);
  unsigned rnd = 0;

  // ================= pre-phase ==============================================
  {
    // out_W -> int8 per-row scale, owner-permuted layout. Wave gw owns rows
    // l = gw + r*4096 (r=0..12), stored at p = gw*13 + r.
    uint2* w8w = (uint2*)(wsb + OFF_W8);
    const float4* src = (const float4*)out_W;
    int gw = bid * 16 + wid;
    for (int r = 0; r < 13; ++r) {
      int l = gw + r * 4096;
      if (r < 12 || l < LANG) {
        int p = gw * 13 + r;
        float4 f[6];
#pragma unroll
        for (int k = 0; k < 3; ++k) {
          f[2 * k]     = src[(size_t)l * 384 + k * 128 + lane * 2];
          f[2 * k + 1] = src[(size_t)l * 384 + k * 128 + lane * 2 + 1];
        }
        float mx = 0.f;
#pragma unroll
        for (int k = 0; k < 6; ++k)
          mx = fmaxf(mx, fmaxf(fmaxf(fabsf(f[k].x), fabsf(f[k].y)),
                               fmaxf(fabsf(f[k].z), fabsf(f[k].w))));
#pragma unroll
        for (int off = 32; off; off >>= 1) mx = fmaxf(mx, __shfl_down(mx, off));
        mx = __shfl(mx, 0);
        float inv = (mx > 0.f) ? 127.f / mx : 0.f;
#pragma unroll
        for (int k = 0; k < 3; ++k) {
          unsigned ux = 0, uy = 0;
          float v0 = f[2 * k].x, v1 = f[2 * k].y, v2 = f[2 * k].z, v3 = f[2 * k].w;
          float v4 = f[2 * k + 1].x, v5 = f[2 * k + 1].y, v6 = f[2 * k + 1].z, v7 = f[2 * k + 1].w;
          ux |= ((unsigned)((int)rintf(v0 * inv) & 255));
          ux |= ((unsigned)((int)rintf(v1 * inv) & 255)) << 8;
          ux |= ((unsigned)((int)rintf(v2 * inv) & 255)) << 16;
          ux |= ((unsigned)((int)rintf(v3 * inv) & 255)) << 24;
          uy |= ((unsigned)((int)rintf(v4 * inv) & 255));
          uy |= ((unsigned)((int)rintf(v5 * inv) & 255)) << 8;
          uy |= ((unsigned)((int)rintf(v6 * inv) & 255)) << 16;
          uy |= ((unsigned)((int)rintf(v7 * inv) & 255)) << 24;
          w8w[(size_t)p * 192 + k * 64 + lane] = make_uint2(ux, uy);
        }
        if (lane == 0) scl[p] = (mx > 0.f) ? mx / 127.f : 0.f;
      }
    }
    // emb_T -> bf16
    uint2* dst2 = (uint2*)(wsb + OFF_EMBTB);
    const float4* src2 = (const float4*)emb_T;
    for (int i = bid * NTHR + tid; i < 6432896; i += NBLK * NTHR) {
      float4 f = src2[i];
      dst2[i] = make_uint2((unsigned)f2bf(f.x) | ((unsigned)f2bf(f.y) << 16),
                           (unsigned)f2bf(f.z) | ((unsigned)f2bf(f.w) << 16));
    }
    // P = emb_src @ W1[:A] + b1  (4 src rows per block)
    for (int i = tid; i < 4 * ADIM; i += NTHR)
      smem[i] = emb_src[(size_t)bid * 4 * ADIM + i];
    __syncthreads();
    if (tid < ADIM) {
      int a = tid;
      float bb = b1[a];
      float a0 = bb, a1 = bb, a2 = bb, a3 = bb;
      for (int k = 0; k < ADIM; ++k) {
        float w = W1[(size_t)k * ADIM + a];
        a0 += smem[k] * w; a1 += smem[512 + k] * w;
        a2 += smem[1024 + k] * w; a3 += smem[1536 + k] * w;
      }
      P[(size_t)(bid * 4 + 0) * ADIM + a] = a0;
      P[(size_t)(bid * 4 + 1) * ADIM + a] = a1;
      P[(size_t)(bid * 4 + 2) * ADIM + a] = a2;
      P[(size_t)(bid * 4 + 3) * ADIM + a] = a3;
    }
    // embT[a][s] = emb_src[s*A + a]
    {
      int i0 = bid * 2048 + tid, i1 = i0 + 1024;
      embT[i0] = emb_src[(size_t)(i0 & 1023) * ADIM + (i0 >> 10)];
      embT[i1] = emb_src[(size_t)(i1 & 1023) * ADIM + (i1 >> 10)];
    }
    if (bid == 0) {
      for (int i = tid; i < 8 * EDIM; i += NTHR)
        eanx8[i] = (i < EDIM) ? emb_T[(size_t)SOSIDX * EDIM + i] : 0.f;
      if (tid < 256) denwp[tid] = (tid == 0) ? 1.0f : 0.0f;
    }
    if (bid == 1) { for (int i = tid; i < 8 * ADIM; i += NTHR) hproj8[i] = 0.f; }
    if (bid == 2) { hws[tid] = hidden[tid]; }
  }
  rnd++; gridbar(bar, bid, rnd);

  for (int t = 0; t < NSTEP; ++t) {
    const int cur = t & 1, nxt = cur ^ 1;
    float* hold = hws + cur * HDIM;
    float* hnew = hws + nxt * HDIM;

    // ==== P1: GRU (+ hproj outer-product scatter) ===========================
    {
      float easum = 0.f;
      if (tid < EDIM) {
#pragma unroll
        for (int k = 0; k < 8; ++k) easum += eanx8[k * EDIM + tid];
      }
      float dp = 0.f;
      if (tid >= 512 && tid < 768) dp = denwp[tid - 512];
      smem[512 + tid] = hold[tid];
      dp = wred(dp);
      if (tid >= 512 && tid < 768 && lane == 0) smem[1632 + (wid - 8)] = dp;
      __syncthreads();
      float inv = 1.0f / (smem[1632] + smem[1633] + smem[1634] + smem[1635]);
      if (tid < EDIM) smem[tid] = easum * inv;
      __syncthreads();

      int jl = wid & 3, part = wid >> 2;
      int j = bid * 4 + jl;
      float ir = 0.f, iz = 0.f, in_ = 0.f;
#pragma unroll
      for (int k = 0; k < 2; ++k) {
        int e = part * 128 + k * 64 + lane;
        float x = smem[e];
        ir  += W_ih[(size_t)j * EDIM + e] * x;
        iz  += W_ih[(size_t)(j + HDIM) * EDIM + e] * x;
        in_ += W_ih[(size_t)(j + 2 * HDIM) * EDIM + e] * x;
      }
      float hr = 0.f, hz = 0.f, hn = 0.f;
#pragma unroll
      for (int k = 0; k < 4; ++k) {
        int e = part * 256 + k * 64 + lane;
        float x = smem[512 + e];
        hr += W_hh[(size_t)j * HDIM + e] * x;
        hz += W_hh[(size_t)(j + HDIM) * HDIM + e] * x;
        hn += W_hh[(size_t)(j + 2 * HDIM) * HDIM + e] * x;
      }
#pragma unroll
      for (int off = 32; off; off >>= 1) {
        ir += __shfl_down(ir, off);  iz += __shfl_down(iz, off);  in_ += __shfl_down(in_, off);
        hr += __shfl_down(hr, off);  hz += __shfl_down(hz, off);  hn += __shfl_down(hn, off);
      }
      if (lane == 0) {
        float* pb = smem + 1536 + (jl * 4 + part) * 6;
        pb[0] = ir; pb[1] = iz; pb[2] = in_; pb[3] = hr; pb[4] = hz; pb[5] = hn;
      }
      __syncthreads();
      if (tid < 4) {
        int jj = bid * 4 + tid;
        float sir = 0.f, siz = 0.f, sin_ = 0.f, shr = 0.f, shz = 0.f, shn = 0.f;
#pragma unroll
        for (int p = 0; p < 4; ++p) {
          float* pb = smem + 1536 + (tid * 4 + p) * 6;
          sir += pb[0]; siz += pb[1]; sin_ += pb[2];
          shr += pb[3]; shz += pb[4]; shn += pb[5];
        }
        float r = 1.f / (1.f + expf(-(sir + b_ih[jj] + shr + b_hh[jj])));
        float z = 1.f / (1.f + expf(-(siz + b_ih[jj + HDIM] + shz + b_hh[jj + HDIM])));
        float n = tanhf(sin_ + b_ih[jj + 2 * HDIM] + r * (shn + b_hh[jj + 2 * HDIM]));
        float hv = (1.f - z) * n + z * smem[512 + jj];
        hnew[jj] = hv;
        smem[1640 + tid] = hv;
      }
      __syncthreads();
      if (tid < ADIM) {
        float s = 0.f;
#pragma unroll
        for (int jl2 = 0; jl2 < 4; ++jl2)
          s += smem[1640 + jl2] * W1[(size_t)(ADIM + bid * 4 + jl2) * ADIM + tid];
        atomicAdd(&hproj8[(bid & 7) * ADIM + tid], s);
      }
    }
    rnd++; gridbar(bar, bid, rnd);

    // ==== P2: scores (reduce hproj8; esc = exp(v.tanh(P+hp)); sdenp) ========
    {
      float hp = 0.f;
      if (tid < ADIM) {
#pragma unroll
        for (int k = 0; k < 8; ++k) hp += hproj8[k * ADIM + tid];
      }
      if (tid >= 512) smem[tid] = vvec[tid - 512];
      if (tid < ADIM) smem[tid] = hp;
      if (bid < 8 && tid < EDIM) eanx8[bid * EDIM + tid] = 0.f;
      __syncthreads();
      int sl = wid & 3, part = wid >> 2;
      int s = bid * 4 + sl;
      float acc = 0.f;
#pragma unroll
      for (int k = 0; k < 2; ++k) {
        int a = part * 128 + k * 64 + lane;
        acc += smem[512 + a] * tanhf(P[(size_t)s * ADIM + a] + smem[a]);
      }
      acc = wred(acc);
      if (lane == 0) smem[1024 + wid] = acc;
      __syncthreads();
      if (tid < 4) {
        float tot = smem[1024 + tid] + smem[1028 + tid] + smem[1032 + tid] + smem[1036 + tid];
        float e = expf(tot);
        esc[bid * 4 + tid] = e;
        smem[1040 + tid] = e;
      }
      __syncthreads();
      if (tid == 0)
        sdenp[bid] = smem[1040] + smem[1041] + smem[1042] + smem[1043];
    }
    rnd++; gridbar(bar, bid, rnd);

    // ==== P3: attn + w output + zero hproj8 =================================
    {
      float sp = 0.f;
      if (tid >= 512 && tid < 768) sp = sdenp[tid - 512];
      sp = wred(sp);
      if (tid >= 512 && tid < 768 && lane == 0) smem[16 + (wid - 8)] = sp;
      int al = wid & 1, part = wid >> 1;
      int a = bid * 2 + al;
      float acc = 0.f;
#pragma unroll
      for (int k = 0; k < 2; ++k) {
        int s = part * 128 + k * 64 + lane;
        acc += embT[(size_t)a * SLEN + s] * esc[s];
      }
      acc = wred(acc);
      if (lane == 0) smem[32 + wid] = acc;
      __syncthreads();
      float sden_t = smem[16] + smem[17] + smem[18] + smem[19];
      if (tid < 2) {
        float s = 0.f;
#pragma unroll
        for (int p = 0; p < 8; ++p) s += smem[32 + tid + p * 2];
        attn[bid * 2 + tid] = s / sden_t;
      }
      if (bid < 4 && tid < 256)
        out[VOFF + (size_t)t * SLEN + bid * 256 + tid] = esc[bid * 256 + tid] / sden_t;
      if (bid < 8 && tid < ADIM) hproj8[bid * ADIM + tid] = 0.f;
    }
    rnd++; gridbar(bar, bid, rnd);

    // ==== P4: int8 logits + word softmax + sparse feedback ==================
    {
      smem[tid] = hnew[tid];
      if (tid < ADIM) smem[HDIM + tid] = attn[tid];
      __syncthreads();
      const float4* sm4 = (const float4*)smem;
      float xr[24];
#pragma unroll
      for (int k = 0; k < 3; ++k) {
        float4 f0 = sm4[k * 128 + lane * 2];
        float4 f1 = sm4[k * 128 + lane * 2 + 1];
        xr[k * 8 + 0] = f0.x; xr[k * 8 + 1] = f0.y; xr[k * 8 + 2] = f0.z; xr[k * 8 + 3] = f0.w;
        xr[k * 8 + 4] = f1.x; xr[k * 8 + 5] = f1.y; xr[k * 8 + 6] = f1.z; xr[k * 8 + 7] = f1.w;
      }
      float* vout = out + (size_t)t * LANG;
      const bool fb = (t + 1 < NSTEP);
      float dsum = 0.f;
      float wmax = -3.4e38f;
      float vvs[13];
      int gw = bid * 16 + wid;
#pragma unroll
      for (int r = 0; r < 13; ++r) {
        float vv = -3.4e38f;
        if (r < 12 || gw < LANG - 49152) {
          int l = gw + r * 4096;
          int p = gw * 13 + r;
          const uint2* base = W8r + (size_t)p * 192;
          uint2 c0 = base[lane];
          uint2 c1 = base[64 + lane];
          uint2 c2 = base[128 + lane];
          float sca = scl[p];
          float acc = 0.f;
          DOT8(c0, 0); DOT8(c1, 1); DOT8(c2, 2);
          acc = wred(acc);
          float bc = __shfl(acc, 0);
          vv = (bc * sca + out_b[l]) * TEMPF;
          if (lane == 0) vout[l] = vv;
          wmax = fmaxf(wmax, vv);
          if (fb) dsum += expf(vv);
        }
        vvs[r] = vv;
      }
      if (lane == 0) { smem[9728 + wid] = wmax; smem[9744 + wid] = dsum; }
      __syncthreads();
      if (fb) {
        if (tid == 0) {
          float tot = 0.f;
#pragma unroll
          for (int p = 0; p < 16; ++p) tot += smem[9744 + p];
          denwp[bid] = tot;
        }
        float bmax = smem[9728];
#pragma unroll
        for (int p = 1; p < 16; ++p) bmax = fmaxf(bmax, smem[9728 + p]);
        float thr = bmax - 12.0f;   // excluded mass <= LANG*e^-12 ~ 3e-4 relative
        float ae[8] = {0.f, 0.f, 0.f, 0.f, 0.f, 0.f, 0.f, 0.f};
#pragma unroll
        for (int r = 0; r < 13; ++r) {
          if (vvs[r] >= thr) {
            int l = gw + r * 4096;
            float ev = expf(vvs[r]);
            uint4 uu = eT4[(size_t)l * 64 + lane];
            ae[0] += ev * __uint_as_float(uu.x << 16);
            ae[1] += ev * __uint_as_float(uu.x & 0xFFFF0000u);
            ae[2] += ev * __uint_as_float(uu.y << 16);
            ae[3] += ev * __uint_as_float(uu.y & 0xFFFF0000u);
            ae[4] += ev * __uint_as_float(uu.z << 16);
            ae[5] += ev * __uint_as_float(uu.z & 0xFFFF0000u);
            ae[6] += ev * __uint_as_float(uu.w << 16);
            ae[7] += ev * __uint_as_float(uu.w & 0xFFFF0000u);
          }
        }
        float* big = smem + 1536;
#pragma unroll
        for (int i = 0; i < 8; ++i) big[wid * 512 + i * 64 + lane] = ae[i];
        __syncthreads();
#pragma unroll
        for (int st = 8; st; st >>= 1) {
          for (int i = tid; i < st * 512; i += NTHR) big[i] += big[i + st * 512];
          __syncthreads();
        }
        if (tid < 512) {
          int dim = ((tid & 63) << 3) | (tid >> 6);
          atomicAdd(&eanx8[(bid & 7) * EDIM + dim], big[tid]);
        }
      }
    }
    rnd++; gridbar(bar, bid, rnd);
  }
}

extern "C" void kernel_launch(void* const* d_in, const int* in_sizes, int n_in,
                              void* d_out, int out_size, void* d_ws, size_t ws_size,
                              hipStream_t stream) {
  const float* hidden  = (const float*)d_in[0];
  const float* emb_src = (const float*)d_in[1];
  const float* emb_T   = (const float*)d_in[2];
  const float* W_ih    = (const float*)d_in[3];
  const float* W_hh    = (const float*)d_in[4];
  const float* b_ih    = (const float*)d_in[5];
  const float* b_hh    = (const float*)d_in[6];
  const float* attn_W1 = (const float*)d_in[7];
  const float* attn_b1 = (const float*)d_in[8];
  const float* attn_v  = (const float*)d_in[9];
  const float* out_W   = (const float*)d_in[10];
  const float* out_b   = (const float*)d_in[11];
  float* out = (float*)d_out;
  char* wsb  = (char*)d_ws;

  hipMemsetAsync(wsb + OFF_BAR, 0, 4096, stream);

  void* args[] = {
    (void*)&hidden, (void*)&emb_src, (void*)&emb_T, (void*)&W_ih, (void*)&W_hh,
    (void*)&b_ih, (void*)&b_hh, (void*)&attn_W1, (void*)&attn_b1, (void*)&attn_v,
    (void*)&out_W, (void*)&out_b, (void*)&out, (void*)&wsb
  };
  hipLaunchCooperativeKernel((void*)k_decoder, dim3(NBLK), dim3(NTHR), args, 0, stream);
}

// Round 8
// 2113.802 us; speedup vs baseline: 2.4307x; 2.4307x over previous
//
#include <hip/hip_runtime.h>
#include <cstddef>
#include <cstdint>

#define LANG 50257
#define EDIM 512
#define HDIM 1024
#define ADIM 512
#define SLEN 1024
#define NSTEP 25
#define TEMPF 10.0f
#define SOSIDX 1
#define VOFF (NSTEP * LANG)
#define NBLK 256
#define NTHR 1024

// ---- ws byte offsets --------------------------------------------------------
#define OFF_W8     0u           // int8 out_W, permuted rows: 53248*1536
#define OFF_SCL    81788928u    // fp32 per-row scale, 53248
#define OFF_EMBTB  82001920u    // bf16 emb_T 50257*512
#define OFF_P      133465088u   // fp32 P[s][a] 1024*512
#define OFF_H      135562240u   // 2*1024
#define OFF_HPROJ8 135570432u   // 8*512
#define OFF_EANX8  135586816u   // 8*512
#define OFF_ATTN8  135603200u   // 8*512
#define OFF_DENWP  135619584u   // 256
#define OFF_SDENP  135620608u   // 256
#define OFF_BAR    135622656u   // flags[256]+gfl[16]+go (memset per launch)

__device__ __forceinline__ float wred(float x) {
#pragma unroll
  for (int off = 32; off; off >>= 1) x += __shfl_down(x, off);
  return x;
}

__device__ __forceinline__ unsigned short f2bf(float x) {
  unsigned u = __float_as_uint(x);
  u = u + 0x7FFFu + ((u >> 16) & 1u);   // RNE
  return (unsigned short)(u >> 16);
}

// device-scope (coherence-point) accesses, NO cache maintenance
__device__ __forceinline__ unsigned gldu(const unsigned* p) {
  return __hip_atomic_load((unsigned*)p, __ATOMIC_RELAXED, __HIP_MEMORY_SCOPE_AGENT);
}
__device__ __forceinline__ void gstu(unsigned* p, unsigned v) {
  __hip_atomic_store(p, v, __ATOMIC_RELAXED, __HIP_MEMORY_SCOPE_AGENT);
}
__device__ __forceinline__ float gldf(const float* p) {
  return __hip_atomic_load((float*)p, __ATOMIC_RELAXED, __HIP_MEMORY_SCOPE_AGENT);
}
__device__ __forceinline__ void gstf(float* p, float v) {
  __hip_atomic_store(p, v, __ATOMIC_RELAXED, __HIP_MEMORY_SCOPE_AGENT);
}

// Fence-free tree barrier: relaxed device-scope flags. Each wave's stores are
// drained (vmcnt 0) before it passes the internal __syncthreads, so data
// precedes the flag at the coherence point.
__device__ __forceinline__ void gridbar(unsigned* bar, int bid, unsigned round) {
  __syncthreads();
  const int tid = threadIdx.x;
  asm volatile("" ::: "memory");
  if (tid < 64) {
    if (tid == 0) {
      asm volatile("s_waitcnt vmcnt(0) lgkmcnt(0)" ::: "memory");
      gstu(&bar[bid], round);
    }
    if ((bid & 15) == 0) {               // group leader wave polls its 16 flags
      unsigned v;
      do { v = (tid < 16) ? gldu(&bar[bid + tid]) : round; } while (__any(v < round));
      if (tid == 0) gstu(&bar[256 + (bid >> 4)], round);
    }
    if (bid == 0) {                      // root polls 16 group flags
      unsigned v;
      do { v = (tid < 16) ? gldu(&bar[256 + tid]) : round; } while (__any(v < round));
      if (tid == 0) gstu(&bar[272], round);
    }
    if (tid == 0) {
      while (gldu(&bar[272]) < round) __builtin_amdgcn_s_sleep(1);
    }
  }
  asm volatile("" ::: "memory");
  __syncthreads();
}

// Fenced variant (used ONCE, to publish plain-stored converted weights).
__device__ __forceinline__ void gridbar_f(unsigned* bar, int bid, unsigned round) {
  __syncthreads();
  if (threadIdx.x == 0) __threadfence();   // wb L2 -> coherence point
  gridbar(bar, bid, round);
  if (threadIdx.x == 0) __threadfence();   // inv stale L2 before reading others' data
  __syncthreads();
}

#define DOT8(u, kk)                                                      \
  {                                                                      \
    acc += (float)((int)((u).x << 24) >> 24) * xr[(kk) * 8 + 0];         \
    acc += (float)((int)((u).x << 16) >> 24) * xr[(kk) * 8 + 1];         \
    acc += (float)((int)((u).x << 8)  >> 24) * xr[(kk) * 8 + 2];         \
    acc += (float)((int)(u).x >> 24)          * xr[(kk) * 8 + 3];        \
    acc += (float)((int)((u).y << 24) >> 24) * xr[(kk) * 8 + 4];         \
    acc += (float)((int)((u).y << 16) >> 24) * xr[(kk) * 8 + 5];         \
    acc += (float)((int)((u).y << 8)  >> 24) * xr[(kk) * 8 + 6];         \
    acc += (float)((int)(u).y >> 24)          * xr[(kk) * 8 + 7];        \
  }

__global__ __launch_bounds__(NTHR, 4) void k_decoder(
    const float* __restrict__ hidden, const float* __restrict__ emb_src,
    const float* __restrict__ emb_T,  const float* __restrict__ W_ih,
    const float* __restrict__ W_hh,   const float* __restrict__ b_ih,
    const float* __restrict__ b_hh,   const float* __restrict__ W1,
    const float* __restrict__ b1,     const float* __restrict__ vvec,
    const float* __restrict__ out_W,  const float* __restrict__ out_b,
    float* __restrict__ out, char* __restrict__ wsb) {
  __shared__ __align__(16) float smem[9776];
  const int tid = threadIdx.x, bid = blockIdx.x;
  const int wid = tid >> 6, lane = tid & 63;

  float* P      = (float*)(wsb + OFF_P);
  float* hws    = (float*)(wsb + OFF_H);
  float* hproj8 = (float*)(wsb + OFF_HPROJ8);
  float* eanx8  = (float*)(wsb + OFF_EANX8);
  float* attn8  = (float*)(wsb + OFF_ATTN8);
  float* denwp  = (float*)(wsb + OFF_DENWP);
  float* sdenp  = (float*)(wsb + OFF_SDENP);
  float* scl    = (float*)(wsb + OFF_SCL);
  unsigned* bar = (unsigned*)(wsb + OFF_BAR);
  const uint2* W8r = (const uint2*)(wsb + OFF_W8);
  const uint4* eT4 = (const uint4*)(wsb + OFF_EMBTB);
  unsigned rnd = 0;

  // ================= pre-phase ==============================================
  {
    // out_W -> int8 per-row scale, owner-permuted (wave gw owns l=gw+r*4096
    // at p=gw*13+r)
    uint2* w8w = (uint2*)(wsb + OFF_W8);
    const float4* src = (const float4*)out_W;
    int gw = bid * 16 + wid;
    for (int r = 0; r < 13; ++r) {
      int l = gw + r * 4096;
      if (r < 12 || l < LANG) {
        int p = gw * 13 + r;
        float4 f[6];
#pragma unroll
        for (int k = 0; k < 3; ++k) {
          f[2 * k]     = src[(size_t)l * 384 + k * 128 + lane * 2];
          f[2 * k + 1] = src[(size_t)l * 384 + k * 128 + lane * 2 + 1];
        }
        float mx = 0.f;
#pragma unroll
        for (int k = 0; k < 6; ++k)
          mx = fmaxf(mx, fmaxf(fmaxf(fabsf(f[k].x), fabsf(f[k].y)),
                               fmaxf(fabsf(f[k].z), fabsf(f[k].w))));
#pragma unroll
        for (int off = 32; off; off >>= 1) mx = fmaxf(mx, __shfl_down(mx, off));
        mx = __shfl(mx, 0);
        float inv = (mx > 0.f) ? 127.f / mx : 0.f;
#pragma unroll
        for (int k = 0; k < 3; ++k) {
          unsigned ux = 0, uy = 0;
          ux |= ((unsigned)((int)rintf(f[2*k].x * inv) & 255));
          ux |= ((unsigned)((int)rintf(f[2*k].y * inv) & 255)) << 8;
          ux |= ((unsigned)((int)rintf(f[2*k].z * inv) & 255)) << 16;
          ux |= ((unsigned)((int)rintf(f[2*k].w * inv) & 255)) << 24;
          uy |= ((unsigned)((int)rintf(f[2*k+1].x * inv) & 255));
          uy |= ((unsigned)((int)rintf(f[2*k+1].y * inv) & 255)) << 8;
          uy |= ((unsigned)((int)rintf(f[2*k+1].z * inv) & 255)) << 16;
          uy |= ((unsigned)((int)rintf(f[2*k+1].w * inv) & 255)) << 24;
          w8w[(size_t)p * 192 + k * 64 + lane] = make_uint2(ux, uy);
        }
        if (lane == 0) scl[p] = (mx > 0.f) ? mx / 127.f : 0.f;
      }
    }
    // emb_T -> bf16
    uint2* dst2 = (uint2*)(wsb + OFF_EMBTB);
    const float4* src2 = (const float4*)emb_T;
    for (int i = bid * NTHR + tid; i < 6432896; i += NBLK * NTHR) {
      float4 f = src2[i];
      dst2[i] = make_uint2((unsigned)f2bf(f.x) | ((unsigned)f2bf(f.y) << 16),
                           (unsigned)f2bf(f.z) | ((unsigned)f2bf(f.w) << 16));
    }
    // P = emb_src @ W1[:A] + b1  (4 src rows per block)
    for (int i = tid; i < 4 * ADIM; i += NTHR)
      smem[i] = emb_src[(size_t)bid * 4 * ADIM + i];
    __syncthreads();
    if (tid < ADIM) {
      int a = tid;
      float bb = b1[a];
      float a0 = bb, a1 = bb, a2 = bb, a3 = bb;
      for (int k = 0; k < ADIM; ++k) {
        float w = W1[(size_t)k * ADIM + a];
        a0 += smem[k] * w; a1 += smem[512 + k] * w;
        a2 += smem[1024 + k] * w; a3 += smem[1536 + k] * w;
      }
      P[(size_t)(bid * 4 + 0) * ADIM + a] = a0;
      P[(size_t)(bid * 4 + 1) * ADIM + a] = a1;
      P[(size_t)(bid * 4 + 2) * ADIM + a] = a2;
      P[(size_t)(bid * 4 + 3) * ADIM + a] = a3;
    }
    if (bid == 0) {
      for (int i = tid; i < 8 * EDIM; i += NTHR)
        eanx8[i] = (i < EDIM) ? emb_T[(size_t)SOSIDX * EDIM + i] : 0.f;
      if (tid < 256) denwp[tid] = (tid == 0) ? 1.0f : 0.0f;
    }
    if (bid == 1) { for (int i = tid; i < 8 * ADIM; i += NTHR) hproj8[i] = 0.f; }
    if (bid == 2) { hws[tid] = hidden[tid]; }
    if (bid == 3) { for (int i = tid; i < 8 * ADIM; i += NTHR) attn8[i] = 0.f; }
  }
  rnd++; gridbar_f(bar, bid, rnd);   // ONE fenced barrier publishes everything

  for (int t = 0; t < NSTEP; ++t) {
    const int cur = t & 1, nxt = cur ^ 1;
    float* hold = hws + cur * HDIM;
    float* hnew = hws + nxt * HDIM;

    // ==== X: GRU + hproj scatter (+ zero attn8 for this step's Y) ===========
    {
      float easum = 0.f;
      if (tid < EDIM) {
#pragma unroll
        for (int k = 0; k < 8; ++k) easum += gldf(&eanx8[k * EDIM + tid]);
      }
      float dp = 0.f;
      if (tid >= 512 && tid < 768) dp = gldf(&denwp[tid - 512]);
      smem[512 + tid] = gldf(&hold[tid]);
      if (bid < 8 && tid < ADIM) gstf(&attn8[bid * ADIM + tid], 0.f);
      dp = wred(dp);
      if (tid >= 512 && tid < 768 && lane == 0) smem[1632 + (wid - 8)] = dp;
      __syncthreads();
      float inv = 1.0f / (smem[1632] + smem[1633] + smem[1634] + smem[1635]);
      if (tid < EDIM) smem[tid] = easum * inv;
      __syncthreads();

      int jl = wid & 3, part = wid >> 2;
      int j = bid * 4 + jl;
      float ir = 0.f, iz = 0.f, in_ = 0.f;
#pragma unroll
      for (int k = 0; k < 2; ++k) {
        int e = part * 128 + k * 64 + lane;
        float x = smem[e];
        ir  += W_ih[(size_t)j * EDIM + e] * x;
        iz  += W_ih[(size_t)(j + HDIM) * EDIM + e] * x;
        in_ += W_ih[(size_t)(j + 2 * HDIM) * EDIM + e] * x;
      }
      float hr = 0.f, hz = 0.f, hn = 0.f;
#pragma unroll
      for (int k = 0; k < 4; ++k) {
        int e = part * 256 + k * 64 + lane;
        float x = smem[512 + e];
        hr += W_hh[(size_t)j * HDIM + e] * x;
        hz += W_hh[(size_t)(j + HDIM) * HDIM + e] * x;
        hn += W_hh[(size_t)(j + 2 * HDIM) * HDIM + e] * x;
      }
#pragma unroll
      for (int off = 32; off; off >>= 1) {
        ir += __shfl_down(ir, off);  iz += __shfl_down(iz, off);  in_ += __shfl_down(in_, off);
        hr += __shfl_down(hr, off);  hz += __shfl_down(hz, off);  hn += __shfl_down(hn, off);
      }
      if (lane == 0) {
        float* pb = smem + 1536 + (jl * 4 + part) * 6;
        pb[0] = ir; pb[1] = iz; pb[2] = in_; pb[3] = hr; pb[4] = hz; pb[5] = hn;
      }
      __syncthreads();
      if (tid < 4) {
        int jj = bid * 4 + tid;
        float sir = 0.f, siz = 0.f, sin_ = 0.f, shr = 0.f, shz = 0.f, shn = 0.f;
#pragma unroll
        for (int p = 0; p < 4; ++p) {
          float* pb = smem + 1536 + (tid * 4 + p) * 6;
          sir += pb[0]; siz += pb[1]; sin_ += pb[2];
          shr += pb[3]; shz += pb[4]; shn += pb[5];
        }
        float r = 1.f / (1.f + expf(-(sir + b_ih[jj] + shr + b_hh[jj])));
        float z = 1.f / (1.f + expf(-(siz + b_ih[jj + HDIM] + shz + b_hh[jj + HDIM])));
        float n = tanhf(sin_ + b_ih[jj + 2 * HDIM] + r * (shn + b_hh[jj + 2 * HDIM]));
        float hv = (1.f - z) * n + z * smem[512 + jj];
        gstf(&hnew[jj], hv);
        smem[1640 + tid] = hv;
      }
      __syncthreads();
      if (tid < ADIM) {
        float s = 0.f;
#pragma unroll
        for (int jl2 = 0; jl2 < 4; ++jl2)
          s += smem[1640 + jl2] * W1[(size_t)(ADIM + bid * 4 + jl2) * ADIM + tid];
        atomicAdd(&hproj8[(bid & 7) * ADIM + tid], s);
      }
    }
    rnd++; gridbar(bar, bid, rnd);

    // ==== Y: scores + sdenp + attn partials (+ zero eanx8) ==================
    {
      float hp = 0.f;
      if (tid < ADIM) {
#pragma unroll
        for (int k = 0; k < 8; ++k) hp += gldf(&hproj8[k * ADIM + tid]);
      }
      if (tid >= 512) smem[tid] = vvec[tid - 512];
      if (tid < ADIM) smem[tid] = hp;
      if (bid < 8 && tid < EDIM) gstf(&eanx8[bid * EDIM + tid], 0.f);
      __syncthreads();
      int sl = wid & 3, part = wid >> 2;
      int s = bid * 4 + sl;
      float acc = 0.f;
#pragma unroll
      for (int k = 0; k < 2; ++k) {
        int a = part * 128 + k * 64 + lane;
        acc += smem[512 + a] * tanhf(P[(size_t)s * ADIM + a] + smem[a]);
      }
      acc = wred(acc);
      if (lane == 0) smem[1024 + wid] = acc;
      __syncthreads();
      if (tid < 4) {
        float tot = smem[1024 + tid] + smem[1028 + tid] + smem[1032 + tid] + smem[1036 + tid];
        float e = expf(tot);
        smem[1040 + tid] = e;
        smem[9764 + tid] = e;     // persists across barrier for Z's w_out
      }
      __syncthreads();
      if (tid == 0)
        gstf(&sdenp[bid], smem[1040] + smem[1041] + smem[1042] + smem[1043]);
      if (tid < ADIM) {
        float pa = smem[1040] * emb_src[(size_t)(bid * 4 + 0) * ADIM + tid]
                 + smem[1041] * emb_src[(size_t)(bid * 4 + 1) * ADIM + tid]
                 + smem[1042] * emb_src[(size_t)(bid * 4 + 2) * ADIM + tid]
                 + smem[1043] * emb_src[(size_t)(bid * 4 + 3) * ADIM + tid];
        atomicAdd(&attn8[(bid & 7) * ADIM + tid], pa);
      }
    }
    rnd++; gridbar(bar, bid, rnd);

    // ==== Z: attn reduce + logits + w_out + feedback (+ zero hproj8) ========
    {
      // gather x = [hnew ; attn8-reduced/sden], sden from sdenp
      float sp = 0.f;
      if (tid >= 512 && tid < 768) sp = gldf(&sdenp[tid - 512]);
      smem[tid] = gldf(&hnew[tid]);
      float a8 = 0.f;
      if (tid < ADIM) {
#pragma unroll
        for (int k = 0; k < 8; ++k) a8 += gldf(&attn8[k * ADIM + tid]);
      }
      if (bid < 8 && tid < ADIM) gstf(&hproj8[bid * ADIM + tid], 0.f);
      sp = wred(sp);
      if (tid >= 512 && tid < 768 && lane == 0) smem[9760 + (wid - 8)] = sp;
      __syncthreads();
      float sden_t = smem[9760] + smem[9761] + smem[9762] + smem[9763];
      if (tid < ADIM) smem[HDIM + tid] = a8 / sden_t;
      if (tid >= 1020)
        out[VOFF + (size_t)t * SLEN + bid * 4 + (tid - 1020)] = smem[9764 + tid - 1020] / sden_t;
      __syncthreads();
      const float4* sm4 = (const float4*)smem;
      float xr[24];
#pragma unroll
      for (int k = 0; k < 3; ++k) {
        float4 f0 = sm4[k * 128 + lane * 2];
        float4 f1 = sm4[k * 128 + lane * 2 + 1];
        xr[k * 8 + 0] = f0.x; xr[k * 8 + 1] = f0.y; xr[k * 8 + 2] = f0.z; xr[k * 8 + 3] = f0.w;
        xr[k * 8 + 4] = f1.x; xr[k * 8 + 5] = f1.y; xr[k * 8 + 6] = f1.z; xr[k * 8 + 7] = f1.w;
      }
      __syncthreads();                  // xr in regs; smem[0..208] reusable
      float* vsl = smem;                // per-wave vv stash 16*13, OUTSIDE big
      float* vout = out + (size_t)t * LANG;
      const bool fb = (t + 1 < NSTEP);
      float dsum = 0.f;
      float wmax = -3.4e38f;
      int gw = bid * 16 + wid;
#pragma unroll
      for (int r = 0; r < 13; ++r) {
        float vv = -3.4e38f;
        if (r < 12 || gw < LANG - 49152) {
          int l = gw + r * 4096;
          int p = gw * 13 + r;
          const uint2* base = W8r + (size_t)p * 192;
          uint2 c0 = base[lane];
          uint2 c1 = base[64 + lane];
          uint2 c2 = base[128 + lane];
          float sca = scl[p];
          float acc = 0.f;
          DOT8(c0, 0); DOT8(c1, 1); DOT8(c2, 2);
          acc = wred(acc);
          float bc = __shfl(acc, 0);
          vv = (bc * sca + out_b[l]) * TEMPF;
          if (lane == 0) vout[l] = vv;
          wmax = fmaxf(wmax, vv);
          if (fb) dsum += expf(vv);
        }
        if (lane == 0) vsl[wid * 13 + r] = vv;
      }
      if (lane == 0) { smem[9728 + wid] = wmax; smem[9744 + wid] = dsum; }
      __syncthreads();
      if (fb) {
        if (tid == 0) {
          float tot = 0.f;
#pragma unroll
          for (int p = 0; p < 16; ++p) tot += smem[9744 + p];
          gstf(&denwp[bid], tot);
        }
        float bmax = smem[9728];
#pragma unroll
        for (int p = 1; p < 16; ++p) bmax = fmaxf(bmax, smem[9728 + p]);
        float thr = bmax - 12.0f;   // excluded mass <= LANG*e^-12 ~ 3e-4 relative
        float ae[8] = {0.f, 0.f, 0.f, 0.f, 0.f, 0.f, 0.f, 0.f};
#pragma unroll
        for (int r = 0; r < 13; ++r) {
          float sv = vsl[wid * 13 + r];
          if (sv >= thr) {
            int l = gw + r * 4096;
            float ev = expf(sv);
            uint4 uu = eT4[(size_t)l * 64 + lane];
            ae[0] += ev * __uint_as_float(uu.x << 16);
            ae[1] += ev * __uint_as_float(uu.x & 0xFFFF0000u);
            ae[2] += ev * __uint_as_float(uu.y << 16);
            ae[3] += ev * __uint_as_float(uu.y & 0xFFFF0000u);
            ae[4] += ev * __uint_as_float(uu.z << 16);
            ae[5] += ev * __uint_as_float(uu.z & 0xFFFF0000u);
            ae[6] += ev * __uint_as_float(uu.w << 16);
            ae[7] += ev * __uint_as_float(uu.w & 0xFFFF0000u);
          }
        }
        __syncthreads();                  // all vsl reads done before big writes
        float* big = smem + 1536;
#pragma unroll
        for (int i = 0; i < 8; ++i) big[wid * 512 + i * 64 + lane] = ae[i];
        __syncthreads();
#pragma unroll
        for (int st = 8; st; st >>= 1) {
          for (int i = tid; i < st * 512; i += NTHR) big[i] += big[i + st * 512];
          __syncthreads();
        }
        if (tid < 512) {
          int dim = ((tid & 63) << 3) | (tid >> 6);
          atomicAdd(&eanx8[(bid & 7) * EDIM + dim], big[tid]);
        }
      }
    }
    rnd++; gridbar(bar, bid, rnd);
  }
}

extern "C" void kernel_launch(void* const* d_in, const int* in_sizes, int n_in,
                              void* d_out, int out_size, void* d_ws, size_t ws_size,
                              hipStream_t stream) {
  const float* hidden  = (const float*)d_in[0];
  const float* emb_src = (const float*)d_in[1];
  const float* emb_T   = (const float*)d_in[2];
  const float* W_ih    = (const float*)d_in[3];
  const float* W_hh    = (const float*)d_in[4];
  const float* b_ih    = (const float*)d_in[5];
  const float* b_hh    = (const float*)d_in[6];
  const float* attn_W1 = (const float*)d_in[7];
  const float* attn_b1 = (const float*)d_in[8];
  const float* attn_v  = (const float*)d_in[9];
  const float* out_W   = (const float*)d_in[10];
  const float* out_b   = (const float*)d_in[11];
  float* out = (float*)d_out;
  char* wsb  = (char*)d_ws;

  hipMemsetAsync(wsb + OFF_BAR, 0, 4096, stream);

  void* args[] = {
    (void*)&hidden, (void*)&emb_src, (void*)&emb_T, (void*)&W_ih, (void*)&W_hh,
    (void*)&b_ih, (void*)&b_hh, (void*)&attn_W1, (void*)&attn_b1, (void*)&attn_v,
    (void*)&out_W, (void*)&out_b, (void*)&out, (void*)&wsb
  };
  hipLaunchCooperativeKernel((void*)k_decoder, dim3(NBLK), dim3(NTHR), args, 0, stream);
}

// Round 11
// 1982.309 us; speedup vs baseline: 2.5920x; 1.0663x over previous
//
#include <hip/hip_runtime.h>
#include <cstddef>
#include <cstdint>

#define LANG 50257
#define EDIM 512
#define HDIM 1024
#define ADIM 512
#define SLEN 1024
#define NSTEP 25
#define TEMPF 10.0f
#define SOSIDX 1
#define VOFF (NSTEP * LANG)
#define NBLK 256
#define NTHR 1024

// ---- ws byte offsets (R8 map) -----------------------------------------------
#define OFF_W8     0u           // int8 out_W, permuted rows: 53248*1536
#define OFF_SCL    81788928u    // fp32 per-row scale, 53248
#define OFF_EMBTB  82001920u    // bf16 emb_T 50257*512
#define OFF_P      133465088u   // fp32 P[s][a] 1024*512
#define OFF_H      135562240u   // 2*1024
#define OFF_HPROJ8 135570432u   // 8*512
#define OFF_EANX8  135586816u   // 8*512
#define OFF_ATTN8  135603200u   // 8*512
#define OFF_DENWP  135619584u   // 256
#define OFF_SDENP  135620608u   // 256
#define OFF_BAR    135622656u   // flags[256]+gfl[16]+go (memset per launch)

__device__ __forceinline__ float wred(float x) {
#pragma unroll
  for (int off = 32; off; off >>= 1) x += __shfl_down(x, off);
  return x;
}

__device__ __forceinline__ unsigned short f2bf(float x) {
  unsigned u = __float_as_uint(x);
  u = u + 0x7FFFu + ((u >> 16) & 1u);   // RNE
  return (unsigned short)(u >> 16);
}

// device-scope (coherence-point) accesses, NO cache maintenance
__device__ __forceinline__ unsigned gldu(const unsigned* p) {
  return __hip_atomic_load((unsigned*)p, __ATOMIC_RELAXED, __HIP_MEMORY_SCOPE_AGENT);
}
__device__ __forceinline__ void gstu(unsigned* p, unsigned v) {
  __hip_atomic_store(p, v, __ATOMIC_RELAXED, __HIP_MEMORY_SCOPE_AGENT);
}
__device__ __forceinline__ float gldf(const float* p) {
  return __hip_atomic_load((float*)p, __ATOMIC_RELAXED, __HIP_MEMORY_SCOPE_AGENT);
}
__device__ __forceinline__ void gstf(float* p, float v) {
  __hip_atomic_store(p, v, __ATOMIC_RELAXED, __HIP_MEMORY_SCOPE_AGENT);
}

// Fence-free tree barrier: relaxed device-scope flags (R8, proven).
__device__ __forceinline__ void gridbar(unsigned* bar, int bid, unsigned round) {
  __syncthreads();
  const int tid = threadIdx.x;
  asm volatile("" ::: "memory");
  if (tid < 64) {
    if (tid == 0) {
      asm volatile("s_waitcnt vmcnt(0) lgkmcnt(0)" ::: "memory");
      gstu(&bar[bid], round);
    }
    if ((bid & 15) == 0) {
      unsigned v;
      do { v = (tid < 16) ? gldu(&bar[bid + tid]) : round; } while (__any(v < round));
      if (tid == 0) gstu(&bar[256 + (bid >> 4)], round);
    }
    if (bid == 0) {
      unsigned v;
      do { v = (tid < 16) ? gldu(&bar[256 + tid]) : round; } while (__any(v < round));
      if (tid == 0) gstu(&bar[272], round);
    }
    if (tid == 0) {
      while (gldu(&bar[272]) < round) __builtin_amdgcn_s_sleep(1);
    }
  }
  asm volatile("" ::: "memory");
  __syncthreads();
}

__device__ __forceinline__ void gridbar_f(unsigned* bar, int bid, unsigned round) {
  __syncthreads();
  if (threadIdx.x == 0) __threadfence();
  gridbar(bar, bid, round);
  if (threadIdx.x == 0) __threadfence();
  __syncthreads();
}

// int8 dot helpers: byte j of row = column j (identity layout)
#define DOTW(w, x0, x1, x2, x3)                                          \
  {                                                                      \
    acc += (float)((int)((w) << 24) >> 24) * (x0);                       \
    acc += (float)((int)((w) << 16) >> 24) * (x1);                       \
    acc += (float)((int)((w) << 8)  >> 24) * (x2);                       \
    acc += (float)((int)(w) >> 24)          * (x3);                      \
  }

__global__ __launch_bounds__(NTHR, 4) void k_decoder(
    const float* __restrict__ hidden, const float* __restrict__ emb_src,
    const float* __restrict__ emb_T,  const float* __restrict__ W_ih,
    const float* __restrict__ W_hh,   const float* __restrict__ b_ih,
    const float* __restrict__ b_hh,   const float* __restrict__ W1,
    const float* __restrict__ b1,     const float* __restrict__ vvec,
    const float* __restrict__ out_W,  const float* __restrict__ out_b,
    float* __restrict__ out, char* __restrict__ wsb) {
  __shared__ __align__(16) float smem[9776];
  const int tid = threadIdx.x, bid = blockIdx.x;
  const int wid = tid >> 6, lane = tid & 63;

  float* P      = (float*)(wsb + OFF_P);
  float* hws    = (float*)(wsb + OFF_H);
  float* hproj8 = (float*)(wsb + OFF_HPROJ8);
  float* eanx8  = (float*)(wsb + OFF_EANX8);
  float* attn8  = (float*)(wsb + OFF_ATTN8);
  float* denwp  = (float*)(wsb + OFF_DENWP);
  float* sdenp  = (float*)(wsb + OFF_SDENP);
  float* scl    = (float*)(wsb + OFF_SCL);
  unsigned* bar = (unsigned*)(wsb + OFF_BAR);
  const uint4* eT4 = (const uint4*)(wsb + OFF_EMBTB);
  unsigned rnd = 0;

  // ================= pre-phase (R8, unchanged) ==============================
  {
    uint2* w8w = (uint2*)(wsb + OFF_W8);
    const float4* src = (const float4*)out_W;
    int gw = bid * 16 + wid;
    for (int r = 0; r < 13; ++r) {
      int l = gw + r * 4096;
      if (r < 12 || l < LANG) {
        int p = gw * 13 + r;
        float4 f[6];
#pragma unroll
        for (int k = 0; k < 3; ++k) {
          f[2 * k]     = src[(size_t)l * 384 + k * 128 + lane * 2];
          f[2 * k + 1] = src[(size_t)l * 384 + k * 128 + lane * 2 + 1];
        }
        float mx = 0.f;
#pragma unroll
        for (int k = 0; k < 6; ++k)
          mx = fmaxf(mx, fmaxf(fmaxf(fabsf(f[k].x), fabsf(f[k].y)),
                               fmaxf(fabsf(f[k].z), fabsf(f[k].w))));
#pragma unroll
        for (int off = 32; off; off >>= 1) mx = fmaxf(mx, __shfl_down(mx, off));
        mx = __shfl(mx, 0);
        float inv = (mx > 0.f) ? 127.f / mx : 0.f;
#pragma unroll
        for (int k = 0; k < 3; ++k) {
          unsigned ux = 0, uy = 0;
          ux |= ((unsigned)((int)rintf(f[2*k].x * inv) & 255));
          ux |= ((unsigned)((int)rintf(f[2*k].y * inv) & 255)) << 8;
          ux |= ((unsigned)((int)rintf(f[2*k].z * inv) & 255)) << 16;
          ux |= ((unsigned)((int)rintf(f[2*k].w * inv) & 255)) << 24;
          uy |= ((unsigned)((int)rintf(f[2*k+1].x * inv) & 255));
          uy |= ((unsigned)((int)rintf(f[2*k+1].y * inv) & 255)) << 8;
          uy |= ((unsigned)((int)rintf(f[2*k+1].z * inv) & 255)) << 16;
          uy |= ((unsigned)((int)rintf(f[2*k+1].w * inv) & 255)) << 24;
          w8w[(size_t)p * 192 + k * 64 + lane] = make_uint2(ux, uy);
        }
        if (lane == 0) scl[p] = (mx > 0.f) ? mx / 127.f : 0.f;
      } else {
        // zero-fill tail rows so pipelined loads read deterministic data
        int p = gw * 13 + r;
#pragma unroll
        for (int k = 0; k < 3; ++k)
          w8w[(size_t)p * 192 + k * 64 + lane] = make_uint2(0u, 0u);
        if (lane == 0) scl[p] = 0.f;
      }
    }
    uint2* dst2 = (uint2*)(wsb + OFF_EMBTB);
    const float4* src2 = (const float4*)emb_T;
    for (int i = bid * NTHR + tid; i < 6432896; i += NBLK * NTHR) {
      float4 f = src2[i];
      dst2[i] = make_uint2((unsigned)f2bf(f.x) | ((unsigned)f2bf(f.y) << 16),
                           (unsigned)f2bf(f.z) | ((unsigned)f2bf(f.w) << 16));
    }
    for (int i = tid; i < 4 * ADIM; i += NTHR)
      smem[i] = emb_src[(size_t)bid * 4 * ADIM + i];
    __syncthreads();
    if (tid < ADIM) {
      int a = tid;
      float bb = b1[a];
      float a0 = bb, a1 = bb, a2 = bb, a3 = bb;
      for (int k = 0; k < ADIM; ++k) {
        float w = W1[(size_t)k * ADIM + a];
        a0 += smem[k] * w; a1 += smem[512 + k] * w;
        a2 += smem[1024 + k] * w; a3 += smem[1536 + k] * w;
      }
      P[(size_t)(bid * 4 + 0) * ADIM + a] = a0;
      P[(size_t)(bid * 4 + 1) * ADIM + a] = a1;
      P[(size_t)(bid * 4 + 2) * ADIM + a] = a2;
      P[(size_t)(bid * 4 + 3) * ADIM + a] = a3;
    }
    if (bid == 0) {
      for (int i = tid; i < 8 * EDIM; i += NTHR)
        eanx8[i] = (i < EDIM) ? emb_T[(size_t)SOSIDX * EDIM + i] : 0.f;
      if (tid < 256) denwp[tid] = (tid == 0) ? 1.0f : 0.0f;
    }
    if (bid == 1) { for (int i = tid; i < 8 * ADIM; i += NTHR) hproj8[i] = 0.f; }
    if (bid == 2) { hws[tid] = hidden[tid]; }
    if (bid == 3) { for (int i = tid; i < 8 * ADIM; i += NTHR) attn8[i] = 0.f; }
  }
  rnd++; gridbar_f(bar, bid, rnd);

  for (int t = 0; t < NSTEP; ++t) {
    const int cur = t & 1, nxt = cur ^ 1;
    float* hold = hws + cur * HDIM;
    float* hnew = hws + nxt * HDIM;

    // ==== X: GRU + hproj scatter (+ zero attn8) — R8 unchanged ==============
    {
      float easum = 0.f;
      if (tid < EDIM) {
#pragma unroll
        for (int k = 0; k < 8; ++k) easum += gldf(&eanx8[k * EDIM + tid]);
      }
      float dp = 0.f;
      if (tid >= 512 && tid < 768) dp = gldf(&denwp[tid - 512]);
      smem[512 + tid] = gldf(&hold[tid]);
      if (bid < 8 && tid < ADIM) gstf(&attn8[bid * ADIM + tid], 0.f);
      dp = wred(dp);
      if (tid >= 512 && tid < 768 && lane == 0) smem[1632 + (wid - 8)] = dp;
      __syncthreads();
      float inv = 1.0f / (smem[1632] + smem[1633] + smem[1634] + smem[1635]);
      if (tid < EDIM) smem[tid] = easum * inv;
      __syncthreads();

      int jl = wid & 3, part = wid >> 2;
      int j = bid * 4 + jl;
      float ir = 0.f, iz = 0.f, in_ = 0.f;
#pragma unroll
      for (int k = 0; k < 2; ++k) {
        int e = part * 128 + k * 64 + lane;
        float x = smem[e];
        ir  += W_ih[(size_t)j * EDIM + e] * x;
        iz  += W_ih[(size_t)(j + HDIM) * EDIM + e] * x;
        in_ += W_ih[(size_t)(j + 2 * HDIM) * EDIM + e] * x;
      }
      float hr = 0.f, hz = 0.f, hn = 0.f;
#pragma unroll
      for (int k = 0; k < 4; ++k) {
        int e = part * 256 + k * 64 + lane;
        float x = smem[512 + e];
        hr += W_hh[(size_t)j * HDIM + e] * x;
        hz += W_hh[(size_t)(j + HDIM) * HDIM + e] * x;
        hn += W_hh[(size_t)(j + 2 * HDIM) * HDIM + e] * x;
      }
#pragma unroll
      for (int off = 32; off; off >>= 1) {
        ir += __shfl_down(ir, off);  iz += __shfl_down(iz, off);  in_ += __shfl_down(in_, off);
        hr += __shfl_down(hr, off);  hz += __shfl_down(hz, off);  hn += __shfl_down(hn, off);
      }
      if (lane == 0) {
        float* pb = smem + 1536 + (jl * 4 + part) * 6;
        pb[0] = ir; pb[1] = iz; pb[2] = in_; pb[3] = hr; pb[4] = hz; pb[5] = hn;
      }
      __syncthreads();
      if (tid < 4) {
        int jj = bid * 4 + tid;
        float sir = 0.f, siz = 0.f, sin_ = 0.f, shr = 0.f, shz = 0.f, shn = 0.f;
#pragma unroll
        for (int p = 0; p < 4; ++p) {
          float* pb = smem + 1536 + (tid * 4 + p) * 6;
          sir += pb[0]; siz += pb[1]; sin_ += pb[2];
          shr += pb[3]; shz += pb[4]; shn += pb[5];
        }
        float r = 1.f / (1.f + expf(-(sir + b_ih[jj] + shr + b_hh[jj])));
        float z = 1.f / (1.f + expf(-(siz + b_ih[jj + HDIM] + shz + b_hh[jj + HDIM])));
        float n = tanhf(sin_ + b_ih[jj + 2 * HDIM] + r * (shn + b_hh[jj + 2 * HDIM]));
        float hv = (1.f - z) * n + z * smem[512 + jj];
        gstf(&hnew[jj], hv);
        smem[1640 + tid] = hv;
      }
      __syncthreads();
      if (tid < ADIM) {
        float s = 0.f;
#pragma unroll
        for (int jl2 = 0; jl2 < 4; ++jl2)
          s += smem[1640 + jl2] * W1[(size_t)(ADIM + bid * 4 + jl2) * ADIM + tid];
        atomicAdd(&hproj8[(bid & 7) * ADIM + tid], s);
      }
    }
    rnd++; gridbar(bar, bid, rnd);

    // ==== Y: scores + sdenp + attn partials (+ zero eanx8) — R8 unchanged ===
    {
      float hp = 0.f;
      if (tid < ADIM) {
#pragma unroll
        for (int k = 0; k < 8; ++k) hp += gldf(&hproj8[k * ADIM + tid]);
      }
      if (tid >= 512) smem[tid] = vvec[tid - 512];
      if (tid < ADIM) smem[tid] = hp;
      if (bid < 8 && tid < EDIM) gstf(&eanx8[bid * EDIM + tid], 0.f);
      __syncthreads();
      int sl = wid & 3, part = wid >> 2;
      int s = bid * 4 + sl;
      float acc = 0.f;
#pragma unroll
      for (int k = 0; k < 2; ++k) {
        int a = part * 128 + k * 64 + lane;
        acc += smem[512 + a] * tanhf(P[(size_t)s * ADIM + a] + smem[a]);
      }
      acc = wred(acc);
      if (lane == 0) smem[1024 + wid] = acc;
      __syncthreads();
      if (tid < 4) {
        float tot = smem[1024 + tid] + smem[1028 + tid] + smem[1032 + tid] + smem[1036 + tid];
        float e = expf(tot);
        smem[1040 + tid] = e;
        smem[9764 + tid] = e;     // persists across barrier for Z's w_out
      }
      __syncthreads();
      if (tid == 0)
        gstf(&sdenp[bid], smem[1040] + smem[1041] + smem[1042] + smem[1043]);
      if (tid < ADIM) {
        float pa = smem[1040] * emb_src[(size_t)(bid * 4 + 0) * ADIM + tid]
                 + smem[1041] * emb_src[(size_t)(bid * 4 + 1) * ADIM + tid]
                 + smem[1042] * emb_src[(size_t)(bid * 4 + 2) * ADIM + tid]
                 + smem[1043] * emb_src[(size_t)(bid * 4 + 3) * ADIM + tid];
        atomicAdd(&attn8[(bid & 7) * ADIM + tid], pa);
      }
    }
    rnd++; gridbar(bar, bid, rnd);

    // ==== Z: 3-deep pipelined int8 logits + feedback ========================
    {
      float sp = 0.f;
      if (tid >= 512 && tid < 768) sp = gldf(&sdenp[tid - 512]);
      smem[tid] = gldf(&hnew[tid]);
      float a8 = 0.f;
      if (tid < ADIM) {
#pragma unroll
        for (int k = 0; k < 8; ++k) a8 += gldf(&attn8[k * ADIM + tid]);
      }
      if (bid < 8 && tid < ADIM) gstf(&hproj8[bid * ADIM + tid], 0.f);
      sp = wred(sp);
      if (tid >= 512 && tid < 768 && lane == 0) smem[9760 + (wid - 8)] = sp;
      __syncthreads();
      float sden_t = smem[9760] + smem[9761] + smem[9762] + smem[9763];
      if (tid < ADIM) smem[HDIM + tid] = a8 / sden_t;
      if (tid >= 1020)
        out[VOFF + (size_t)t * SLEN + bid * 4 + (tid - 1020)] = smem[9764 + tid - 1020] / sden_t;
      __syncthreads();
      const float4* sm4 = (const float4*)smem;
      // x in regs: xr[0..15] = x[lane*16..+15]; xr[16..23] = x[1024+lane*8..+7]
      float xr[24];
#pragma unroll
      for (int k = 0; k < 4; ++k) {
        float4 f = sm4[lane * 4 + k];
        xr[k * 4 + 0] = f.x; xr[k * 4 + 1] = f.y; xr[k * 4 + 2] = f.z; xr[k * 4 + 3] = f.w;
      }
#pragma unroll
      for (int k = 0; k < 2; ++k) {
        float4 f = sm4[256 + lane * 2 + k];
        xr[16 + k * 4 + 0] = f.x; xr[16 + k * 4 + 1] = f.y;
        xr[16 + k * 4 + 2] = f.z; xr[16 + k * 4 + 3] = f.w;
      }
      int gw = bid * 16 + wid;
      float myscl = 0.f, myob = 0.f;
      if (lane < 13) {
        myscl = scl[gw * 13 + lane];
        int l0 = gw + lane * 4096;
        myob = (l0 < LANG) ? out_b[l0] : 0.f;
      }
      float* vsl = smem;                // reuses x region (xr now in regs) — but
      // x smem[0..1536) is still live for OTHER waves? No: every wave reads only
      // its own lane slice into regs above, then __syncthreads guarantees done.
      __syncthreads();
      float* vout = out + (size_t)t * LANG;
      const bool fb = (t + 1 < NSTEP);
      float dsum = 0.f;
      float wmax = -3.4e38f;
      const char* wbase = wsb + OFF_W8 + (size_t)(gw * 13) * 1536;
      const uint4* r4b = (const uint4*)wbase;          // row r: [r*96 + lane]
      const uint2* r2b = (const uint2*)(wbase + 1024); // row r: [r*192 + lane]
      uint4 q4[3]; uint2 q2[3];
      q4[0] = r4b[0 * 96 + lane];  q2[0] = r2b[0 * 192 + lane];
      q4[1] = r4b[1 * 96 + lane];  q2[1] = r2b[1 * 192 + lane];
      q4[2] = r4b[2 * 96 + lane];  q2[2] = r2b[2 * 192 + lane];
#pragma unroll
      for (int r = 0; r < 13; ++r) {
        uint4 c4 = q4[r % 3];
        uint2 c2 = q2[r % 3];
        if (r + 3 < 13) {
          q4[r % 3] = r4b[(r + 3) * 96 + lane];
          q2[r % 3] = r2b[(r + 3) * 192 + lane];
        }
        float acc = 0.f;
        DOTW(c4.x, xr[0], xr[1], xr[2], xr[3]);
        DOTW(c4.y, xr[4], xr[5], xr[6], xr[7]);
        DOTW(c4.z, xr[8], xr[9], xr[10], xr[11]);
        DOTW(c4.w, xr[12], xr[13], xr[14], xr[15]);
        DOTW(c2.x, xr[16], xr[17], xr[18], xr[19]);
        DOTW(c2.y, xr[20], xr[21], xr[22], xr[23]);
        acc = wred(acc);
        float vv = -3.4e38f;
        if (r < 12 || gw < LANG - 49152) {
          float bc = __shfl(acc, 0);
          float sca = __shfl(myscl, r);
          float ob  = __shfl(myob, r);
          vv = (bc * sca + ob) * TEMPF;
          if (lane == 0) vout[gw + r * 4096] = vv;
          wmax = fmaxf(wmax, vv);
          if (fb) dsum += expf(vv);
        }
        if (lane == 0) vsl[wid * 13 + r] = vv;
      }
      if (lane == 0) { smem[624 + wid] = wmax; smem[640 + wid] = dsum; }
      __syncthreads();
      if (fb) {
        if (tid == 0) {
          float tot = 0.f;
#pragma unroll
          for (int p = 0; p < 16; ++p) tot += smem[640 + p];
          gstf(&denwp[bid], tot);
        }
        float bmax = smem[624];
#pragma unroll
        for (int p = 1; p < 16; ++p) bmax = fmaxf(bmax, smem[624 + p]);
        float thr = bmax - 12.0f;   // excluded mass <= LANG*e^-12 ~ 3e-4 relative
        float ae[8] = {0.f, 0.f, 0.f, 0.f, 0.f, 0.f, 0.f, 0.f};
#pragma unroll
        for (int r = 0; r < 13; ++r) {
          float sv = vsl[wid * 13 + r];
          if (sv >= thr) {
            int l = gw + r * 4096;
            float ev = expf(sv);
            uint4 uu = eT4[(size_t)l * 64 + lane];
            ae[0] += ev * __uint_as_float(uu.x << 16);
            ae[1] += ev * __uint_as_float(uu.x & 0xFFFF0000u);
            ae[2] += ev * __uint_as_float(uu.y << 16);
            ae[3] += ev * __uint_as_float(uu.y & 0xFFFF0000u);
            ae[4] += ev * __uint_as_float(uu.z << 16);
            ae[5] += ev * __uint_as_float(uu.z & 0xFFFF0000u);
            ae[6] += ev * __uint_as_float(uu.w << 16);
            ae[7] += ev * __uint_as_float(uu.w & 0xFFFF0000u);
          }
        }
        __syncthreads();                  // all vsl reads done before big writes
        float* big = smem + 1536;
#pragma unroll
        for (int i = 0; i < 8; ++i) big[wid * 512 + i * 64 + lane] = ae[i];
        __syncthreads();
#pragma unroll
        for (int st = 8; st; st >>= 1) {
          for (int i = tid; i < st * 512; i += NTHR) big[i] += big[i + st * 512];
          __syncthreads();
        }
        if (tid < 512) {
          int dim = ((tid & 63) << 3) | (tid >> 6);
          atomicAdd(&eanx8[(bid & 7) * EDIM + dim], big[tid]);
        }
      }
    }
    rnd++; gridbar(bar, bid, rnd);
  }
}

extern "C" void kernel_launch(void* const* d_in, const int* in_sizes, int n_in,
                              void* d_out, int out_size, void* d_ws, size_t ws_size,
                              hipStream_t stream) {
  const float* hidden  = (const float*)d_in[0];
  const float* emb_src = (const float*)d_in[1];
  const float* emb_T   = (const float*)d_in[2];
  const float* W_ih    = (const float*)d_in[3];
  const float* W_hh    = (const float*)d_in[4];
  const float* b_ih    = (const float*)d_in[5];
  const float* b_hh    = (const float*)d_in[6];
  const float* attn_W1 = (const float*)d_in[7];
  const float* attn_b1 = (const float*)d_in[8];
  const float* attn_v  = (const float*)d_in[9];
  const float* out_W   = (const float*)d_in[10];
  const float* out_b   = (const float*)d_in[11];
  float* out = (float*)d_out;
  char* wsb  = (char*)d_ws;

  hipMemsetAsync(wsb + OFF_BAR, 0, 4096, stream);

  void* args[] = {
    (void*)&hidden, (void*)&emb_src, (void*)&emb_T, (void*)&W_ih, (void*)&W_hh,
    (void*)&b_ih, (void*)&b_hh, (void*)&attn_W1, (void*)&attn_b1, (void*)&attn_v,
    (void*)&out_W, (void*)&out_b, (void*)&out, (void*)&wsb
  };
  hipLaunchCooperativeKernel((void*)k_decoder, dim3(NBLK), dim3(NTHR), args, 0, stream);
}